// Round 1
// baseline (288.945 us; speedup 1.0000x reference)
//
#include <hip/hip_runtime.h>
#include <hip/hip_bf16.h>

typedef __attribute__((ext_vector_type(8))) short short8;
typedef __attribute__((ext_vector_type(4))) float f32x4;
typedef __attribute__((ext_vector_type(16))) float f32x16;
typedef __attribute__((ext_vector_type(2))) unsigned int uint2v;
typedef __attribute__((ext_vector_type(4))) unsigned int uint4v;

#define SEQ    2048
#define DM     1024
#define NH     16
#define DH     64
#define NBATCH 4
#define MTOK   (NBATCH * SEQ)                       // 8192 tokens
#define SEG    ((size_t)NBATCH * NH * SEQ * DH)     // 8388608 elems per Q/K/V buffer
// Q pre-scaled by 1/sqrt(64) * log2(e) so attention inner loop is exp2 only.
#define QSCALE 0.18033688f

// Fast RNE float->bf16 for FINITE values: bf16 bits land in the high 16.
static __device__ __forceinline__ unsigned bfbits(float f) {
  unsigned u = __float_as_uint(f);
  return u + 0x7fffu + ((u >> 16) & 1u);
}
static __device__ __forceinline__ unsigned short f2bf(float f) {
  return (unsigned short)(bfbits(f) >> 16);
}
// RNE pack of two floats to packed bf16x2 (lo in low half).
static __device__ __forceinline__ unsigned pack2bf(float lo, float hi) {
  return __builtin_amdgcn_perm(bfbits(hi), bfbits(lo), 0x07060302u);
}
// Truncation pack (round-toward-zero for positives): 1 v_perm on raw bits.
static __device__ __forceinline__ unsigned pack2tr(unsigned ulo, unsigned uhi) {
  return __builtin_amdgcn_perm(uhi, ulo, 0x07060302u);
}

typedef const __attribute__((address_space(1))) unsigned int* gp_t;
typedef __attribute__((address_space(3))) unsigned int* lp_t;
static __device__ __forceinline__ void gload_lds16(const void* g, void* l) {
  __builtin_amdgcn_global_load_lds((gp_t)g, (lp_t)l, 16, 0, 0);
}

// ---------------------------------------------------------------------------
// x fp32 -> bf16 cast (8 elems/thread).
// ---------------------------------------------------------------------------
__global__ __launch_bounds__(256) void xcast(const float* __restrict__ x,
                                             unsigned short* __restrict__ xb) {
  size_t i = ((size_t)blockIdx.x * 256 + threadIdx.x) * 8;
  f32x4 a = *(const f32x4*)&x[i];
  f32x4 b = *(const f32x4*)&x[i + 4];
  uint4v s;
  s[0] = pack2bf(a[0], a[1]);
  s[1] = pack2bf(a[2], a[3]);
  s[2] = pack2bf(b[0], b[1]);
  s[3] = pack2bf(b[2], b[3]);
  *(uint4v*)&xb[i] = s;
}

// ---------------------------------------------------------------------------
// Weight transpose: W [K][N] fp32 -> WT [N][K] bf16. 64x64 tiles, 256 thr.
// ---------------------------------------------------------------------------
__global__ __launch_bounds__(256) void transpose_w(
    const float* __restrict__ W, unsigned short* __restrict__ WT, int K, int N) {
  __shared__ float T[64][65];
  const int tid = threadIdx.x;
  const int n0 = blockIdx.x * 64;
  const int k0 = blockIdx.y * 64;
#pragma unroll
  for (int it = 0; it < 4; it++) {
    int row = it * 16 + (tid >> 4);
    int c4 = (tid & 15) * 4;
    f32x4 v = *(const f32x4*)&W[(size_t)(k0 + row) * N + n0 + c4];
#pragma unroll
    for (int j = 0; j < 4; j++) T[row][c4 + j] = v[j];
  }
  __syncthreads();
#pragma unroll
  for (int it = 0; it < 2; it++) {
    int chunk = tid + it * 256;
    int n = chunk >> 3;
    int c8 = (chunk & 7) * 8;
    uint4v s;
#pragma unroll
    for (int j = 0; j < 4; j++)
      s[j] = pack2bf(T[c8 + 2 * j][n], T[c8 + 2 * j + 1][n]);
    *(uint4v*)&WT[(size_t)(n0 + n) * K + k0 + c8] = s;
  }
}

// ---------------------------------------------------------------------------
// GEMM: C[M,N] = A[M,K] @ BT[N,K]^T, fp32 accum. 128x128 tile, BK=64,
// 256 threads (4 waves 2x2). Tiles stored with granule-XOR swizzle:
// LDS[r][g] holds global granule (g ^ (r&7)) of row r (granule = 8 shorts).
// -> conflict-free b128 fragment reads; DMA staging swizzles the SOURCE.
// MODE 0: A fp32 (VALU cvt staging); QKV scatter epilogue (V transposed).
// MODE 2: A bf16 (DMA staging);      QKV scatter epilogue (V transposed).
// MODE 1: A bf16 (DMA staging);      fp32 row-major output.
// ---------------------------------------------------------------------------
template <int MODE>
__global__ __launch_bounds__(256) void gemm_kernel(
    const void* __restrict__ Av, const unsigned short* __restrict__ BT,
    unsigned short* __restrict__ out0, unsigned short* __restrict__ out1,
    unsigned short* __restrict__ out2, float* __restrict__ outf,
    int M, int N, int K) {
  __shared__ unsigned short As[128][64];
  __shared__ unsigned short Bs[128][64];

  const int tid = threadIdx.x;
  const int wave = tid >> 6;
  const int lane = tid & 63;
  const int quad = lane >> 4;
  const int lc = lane & 15;
  const int wr = wave >> 1;
  const int wc = wave & 1;
  const int m0 = blockIdx.y * 128;
  const int n0 = blockIdx.x * 128;
  const int xsw = lc & 7;               // fragment-read swizzle key
  const int lr8 = lane >> 3;            // staging: row within 8-row group
  const int sgo = ((lane & 7) ^ (lr8 & 7)) * 8;  // swizzled source offset

  f32x4 acc[4][4];
#pragma unroll
  for (int i = 0; i < 4; i++)
#pragma unroll
    for (int j = 0; j < 4; j++) acc[i][j] = (f32x4){0.f, 0.f, 0.f, 0.f};

  for (int k0 = 0; k0 < K; k0 += 64) {
    // ---- Stage A tile (128 x 64) ----
    if (MODE == 0) {
      const float* A = (const float*)Av;
#pragma unroll
      for (int i = 0; i < 4; i++) {
        int chunk = tid + i * 256;      // 1024 granules
        int r = chunk >> 3;
        int g = chunk & 7;
        int scol = (g ^ (r & 7)) * 8;
        f32x4 v0 = *(const f32x4*)&A[(size_t)(m0 + r) * K + k0 + scol];
        f32x4 v1 = *(const f32x4*)&A[(size_t)(m0 + r) * K + k0 + scol + 4];
        uint4v s;
        s[0] = pack2bf(v0[0], v0[1]);
        s[1] = pack2bf(v0[2], v0[3]);
        s[2] = pack2bf(v1[0], v1[1]);
        s[3] = pack2bf(v1[2], v1[3]);
        *(uint4v*)&As[r][g * 8] = s;
      }
    } else {
      const unsigned short* A = (const unsigned short*)Av;
#pragma unroll
      for (int it = 0; it < 4; it++) {
        int rbase = wave * 32 + it * 8;  // 8 rows = 1 KB per instruction
        gload_lds16(&A[(size_t)(m0 + rbase + lr8) * K + k0 + sgo],
                    &As[rbase][0]);
      }
    }
    // ---- Stage B tile (128 n-rows x 64 k) ----
#pragma unroll
    for (int it = 0; it < 4; it++) {
      int rbase = wave * 32 + it * 8;
      gload_lds16(&BT[(size_t)(n0 + rbase + lr8) * K + k0 + sgo],
                  &Bs[rbase][0]);
    }
    __syncthreads();

#pragma unroll
    for (int kc = 0; kc < 2; kc++) {
      short8 aA[4], bB[4];
#pragma unroll
      for (int mt = 0; mt < 4; mt++)
        aA[mt] = *(const short8*)&As[wr * 64 + mt * 16 + lc]
                                    [((kc * 4 + quad) ^ xsw) * 8];
#pragma unroll
      for (int nt = 0; nt < 4; nt++)
        bB[nt] = *(const short8*)&Bs[wc * 64 + nt * 16 + lc]
                                    [((kc * 4 + quad) ^ xsw) * 8];
#pragma unroll
      for (int mt = 0; mt < 4; mt++)
#pragma unroll
        for (int nt = 0; nt < 4; nt++)
          acc[mt][nt] = __builtin_amdgcn_mfma_f32_16x16x32_bf16(
              aA[mt], bB[nt], acc[mt][nt], 0, 0, 0);
    }
    __syncthreads();
  }

  // Epilogue: C/D layout col=lane&15, row=quad*4+reg.
  const int c = n0 >> 10;  // QKV segment (block-uniform): 0=Q 1=K 2=V
#pragma unroll
  for (int mt = 0; mt < 4; mt++)
#pragma unroll
    for (int nt = 0; nt < 4; nt++) {
      int rb = m0 + wr * 64 + mt * 16 + quad * 4;  // 4 consecutive tokens
      int col = n0 + wc * 64 + nt * 16 + lc;
      if (MODE == 1) {
#pragma unroll
        for (int r = 0; r < 4; r++)
          outf[(size_t)(rb + r) * N + col] = acc[mt][nt][r];
      } else {
        int rem = col & 1023;
        int h = rem >> 6;
        int dd = rem & 63;
        int b = rb >> 11;
        int tt = rb & 2047;
        if (c == 2) {
          uint2v pk;
          pk[0] = pack2bf(acc[mt][nt][0], acc[mt][nt][1]);
          pk[1] = pack2bf(acc[mt][nt][2], acc[mt][nt][3]);
          *(uint2v*)&out2[(((size_t)(b * NH + h)) * DH + dd) * SEQ + tt] = pk;
        } else {
          unsigned short* dst = (c == 0) ? out0 : out1;
          float sc = (c == 0) ? QSCALE : 1.0f;
#pragma unroll
          for (int r = 0; r < 4; r++)
            dst[(((size_t)(b * NH + h) * SEQ + tt + r) << 6) + dd] =
                f2bf(acc[mt][nt][r] * sc);
        }
      }
    }
}

// ---------------------------------------------------------------------------
// Flash attention. Q,K: [bh][T][64] bf16 (Q pre-scaled); Vt: [bh][64][T] bf16.
// Block = 256 thr = 4 waves; wave owns 32 q-rows (block 128); 64-key tiles.
// S^T = K·Q^T via 32x32x16 MFMA -> 4 consecutive keys per lane. P packed by
// TRUNCATION (1 v_perm / pair); l accumulates the SAME truncated values so
// normalization is self-consistent.
// NEW vs prev round:
//  * P half-exchange in-register via v_permlane32_swap_b32 (T12) — the Ps
//    LDS round-trip (12 ds-ops/tile/lane, 2-way conflicts = 8.4M cycles) is
//    replaced by 8 permlanes/tile. PV now interleaved per 32-key block.
//  * K/Vt double-buffered (T3-minimal): stage t+1 -> compute t -> barrier.
//    One barrier per tile; staging latency hides under compute.
//  * s_setprio(1) around MFMA clusters (T5).
// ---------------------------------------------------------------------------
__global__ __launch_bounds__(256) void attn_kernel(
    const unsigned short* __restrict__ Q, const unsigned short* __restrict__ K,
    const unsigned short* __restrict__ Vt, unsigned short* __restrict__ ctx) {
  __shared__ unsigned short KsL[2][64 * 64];  // granule-swizzled [key][d]
  __shared__ unsigned short VtL[2][64 * 64];  // granule-swizzled [d][key]
  __shared__ float lbuf[4][32];               // 1/l per q-row

  const int tid = threadIdx.x;
  const int wave = tid >> 6;
  const int lane = tid & 63;
  const int half = lane >> 5;
  const int l31 = lane & 31;
  const int bh = blockIdx.y;
  const int q0 = blockIdx.x * 128 + wave * 32;
  const size_t kqbase = (size_t)bh * SEQ * DH;
  const size_t vbase = (size_t)bh * DH * SEQ;

  // Q B-fragments (n=qrow=l31, k=d): 4 d-chunks of 16.
  short8 bQ[4];
#pragma unroll
  for (int dc = 0; dc < 4; dc++)
    bQ[dc] = *(const short8*)&Q[kqbase + (size_t)(q0 + l31) * DH + dc * 16 + half * 8];

  f32x16 o[2];
#pragma unroll
  for (int nb = 0; nb < 2; nb++)
#pragma unroll
    for (int j = 0; j < 16; j++) o[nb][j] = 0.f;
  float l_part = 0.f;

  const int xsw = l31 & 7;  // bank-swizzle key for this lane's fragment rows
  // Hoisted staging geometry (granule id = wave*128 + it*64 + lane).
  const int g0 = wave * 128 + lane;
  const int r0 = g0 >> 3, r1 = (g0 + 64) >> 3;
  const size_t so0 = (size_t)r0 * DH + (((g0 & 7) ^ (r0 & 7)) * 8);
  const size_t so1 = (size_t)r1 * DH + (((g0 & 7) ^ (r1 & 7)) * 8);
  const size_t sv0 = (size_t)r0 * SEQ + (((g0 & 7) ^ (r0 & 7)) * 8);
  const size_t sv1 = (size_t)r1 * SEQ + (((g0 & 7) ^ (r1 & 7)) * 8);
  const int ldo = wave * 1024;  // this wave's staging region (shorts)

  auto stage = [&](int kt, int b) {
    const size_t kg = kqbase + (size_t)kt * 64 * DH;
    const size_t vg = vbase + (size_t)kt * 64;
    unsigned short* kd = &KsL[b][ldo];
    unsigned short* vd = &VtL[b][ldo];
    gload_lds16(&K[kg + so0], kd);
    gload_lds16(&K[kg + so1], kd + 512);
    gload_lds16(&Vt[vg + sv0], vd);
    gload_lds16(&Vt[vg + sv1], vd + 512);
  };

  stage(0, 0);
  __syncthreads();

  for (int kt = 0; kt < SEQ / 64; kt++) {
    const int cur = kt & 1;
    if (kt + 1 < SEQ / 64) stage(kt + 1, cur ^ 1);  // prefetch next tile
    const unsigned short* kcur = &KsL[cur][0];
    const unsigned short* vcur = &VtL[cur][0];

    // S^T = K·Q^T : two 32-key blocks, contraction d=64 (4 chained MFMA),
    // then softmax+pack and P·V for that key-block (in-register exchange).
#pragma unroll
    for (int kb = 0; kb < 2; kb++) {
      f32x16 s;
#pragma unroll
      for (int j = 0; j < 16; j++) s[j] = 0.f;
      __builtin_amdgcn_s_setprio(1);
#pragma unroll
      for (int dc = 0; dc < 4; dc++) {
        const short8 aK = *(const short8*)&kcur[(size_t)(kb * 32 + l31) * 64 +
                                                ((dc * 2 + half) ^ xsw) * 8];
        s = __builtin_amdgcn_mfma_f32_32x32x16_bf16(aK, bQ[dc], s, 0, 0, 0);
      }
      __builtin_amdgcn_s_setprio(0);

      // p = exp2(s); truncate to bf16; l sums the truncated values.
      // Lane (l31,half) holds keys kb*32 + gq*8 + half*4 + {0..3} as packed
      // dwords d0[gq] (keys +0,1) and d1[gq] (keys +2,3).
      unsigned d0[4], d1[4];
#pragma unroll
      for (int gq = 0; gq < 4; gq++) {
        unsigned u0 = __float_as_uint(__builtin_amdgcn_exp2f(s[gq * 4 + 0]));
        unsigned u1 = __float_as_uint(__builtin_amdgcn_exp2f(s[gq * 4 + 1]));
        unsigned u2 = __float_as_uint(__builtin_amdgcn_exp2f(s[gq * 4 + 2]));
        unsigned u3 = __float_as_uint(__builtin_amdgcn_exp2f(s[gq * 4 + 3]));
        float t0 = __uint_as_float(u0 & 0xffff0000u);
        float t1 = __uint_as_float(u1 & 0xffff0000u);
        float t2 = __uint_as_float(u2 & 0xffff0000u);
        float t3 = __uint_as_float(u3 & 0xffff0000u);
        l_part += (t0 + t1) + (t2 + t3);
        d0[gq] = pack2tr(u0, u1);
        d1[gq] = pack2tr(u2, u3);
      }

      // O += P·V for this 32-key block: chunks kc = kb*2 + {0,1}.
      // A-fragment dwords for chunk: w0..w3 = keys chunk*16 + half*8 + pairs.
      // v_permlane32_swap_b32 exchanges a.hi-lanes with b.lo-lanes:
      //   swap(d0[2k], d0[2k+1]) -> (w0, w2); swap(d1[2k], d1[2k+1]) -> (w1, w3).
#pragma unroll
      for (int kcl = 0; kcl < 2; kcl++) {
        unsigned w0 = d0[kcl * 2], w2 = d0[kcl * 2 + 1];
        unsigned w1 = d1[kcl * 2], w3 = d1[kcl * 2 + 1];
        asm("v_permlane32_swap_b32 %0, %1" : "+v"(w0), "+v"(w2));
        asm("v_permlane32_swap_b32 %0, %1" : "+v"(w1), "+v"(w3));
        union { unsigned u[4]; short8 s8; } cv;
        cv.u[0] = w0; cv.u[1] = w1; cv.u[2] = w2; cv.u[3] = w3;
        const int kc = kb * 2 + kcl;
        __builtin_amdgcn_s_setprio(1);
#pragma unroll
        for (int nb = 0; nb < 2; nb++) {
          const short8 bV = *(const short8*)&vcur[(size_t)(nb * 32 + l31) * 64 +
                                                  ((kc * 2 + half) ^ xsw) * 8];
          o[nb] = __builtin_amdgcn_mfma_f32_32x32x16_bf16(cv.s8, bV, o[nb], 0, 0, 0);
        }
        __builtin_amdgcn_s_setprio(0);
      }
    }
    __syncthreads();  // staged next tile complete; buffers free for overwrite
  }

  // l: both halves hold partial sums for qrow=l31 -> combine; store 1/l.
  l_part += __shfl_xor(l_part, 32);
  lbuf[wave][l31] = 1.0f / l_part;
  __syncthreads();

  const int b = bh >> 4;
  const int h = bh & 15;
#pragma unroll
  for (int gq = 0; gq < 4; gq++)
#pragma unroll
    for (int j = 0; j < 4; j++) {
      int ql = j + gq * 8 + half * 4;  // q within wave (C-layout row)
      float inv = lbuf[wave][ql];
      int token = blockIdx.x * 128 + wave * 32 + ql;
#pragma unroll
      for (int nb = 0; nb < 2; nb++)
        ctx[((size_t)b * SEQ + token) * DM + h * DH + nb * 32 + l31] =
            f2bf(o[nb][gq * 4 + j] * inv);
    }
}

extern "C" void kernel_launch(void* const* d_in, const int* in_sizes, int n_in,
                              void* d_out, int out_size, void* d_ws,
                              size_t ws_size, hipStream_t stream) {
  const float* x = (const float*)d_in[0];     // [8192,1024] fp32
  const float* Wqkv = (const float*)d_in[1];  // [1024,3072] fp32
  const float* Wo = (const float*)d_in[2];    // [1024,1024] fp32
  float* out = (float*)d_out;                 // [8192,1024] fp32
  unsigned short* ws = (unsigned short*)d_ws;

  unsigned short* Qb = ws;                          // [bh][T][64], pre-scaled
  unsigned short* Kb = ws + SEG;                    // [bh][T][64]
  unsigned short* Vt = ws + 2 * SEG;                // [bh][64][T]
  unsigned short* Ctx = ws + 3 * SEG;               // [8192][1024]
  unsigned short* WqT = Ctx + (size_t)MTOK * DM;    // [3072][1024]
  unsigned short* WoT = WqT + (size_t)3 * DM * DM;  // [1024][1024]
  unsigned short* Xb = WoT + (size_t)DM * DM;       // [8192][1024]
  const size_t need =
      ((size_t)(Xb - ws) + (size_t)MTOK * DM) * sizeof(unsigned short);

  transpose_w<<<dim3(3 * DM / 64, DM / 64), 256, 0, stream>>>(Wqkv, WqT, DM, 3 * DM);
  transpose_w<<<dim3(DM / 64, DM / 64), 256, 0, stream>>>(Wo, WoT, DM, DM);

  if (ws_size >= need) {
    xcast<<<(MTOK * DM) / (256 * 8), 256, 0, stream>>>(x, Xb);
    gemm_kernel<2><<<dim3(3 * DM / 128, MTOK / 128), 256, 0, stream>>>(
        (const void*)Xb, WqT, Qb, Kb, Vt, nullptr, MTOK, 3 * DM, DM);
  } else {
    gemm_kernel<0><<<dim3(3 * DM / 128, MTOK / 128), 256, 0, stream>>>(
        (const void*)x, WqT, Qb, Kb, Vt, nullptr, MTOK, 3 * DM, DM);
  }
  attn_kernel<<<dim3(SEQ / 128, NBATCH * NH), 256, 0, stream>>>(Qb, Kb, Vt, Ctx);
  gemm_kernel<1><<<dim3(DM / 128, MTOK / 128), 256, 0, stream>>>(
      (const void*)Ctx, WoT, nullptr, nullptr, nullptr, out, MTOK, DM, DM);
}

// Round 2
// 283.743 us; speedup vs baseline: 1.0183x; 1.0183x over previous
//
#include <hip/hip_runtime.h>
#include <hip/hip_bf16.h>

typedef __attribute__((ext_vector_type(8))) short short8;
typedef __attribute__((ext_vector_type(4))) float f32x4;
typedef __attribute__((ext_vector_type(16))) float f32x16;
typedef __attribute__((ext_vector_type(2))) unsigned int uint2v;
typedef __attribute__((ext_vector_type(4))) unsigned int uint4v;

#define SEQ    2048
#define DM     1024
#define NH     16
#define DH     64
#define NBATCH 4
#define MTOK   (NBATCH * SEQ)                       // 8192 tokens
#define SEG    ((size_t)NBATCH * NH * SEQ * DH)     // 8388608 elems per Q/K/V buffer
// Q pre-scaled by 1/sqrt(64) * log2(e) so attention inner loop is exp2 only.
#define QSCALE 0.18033688f

// Fast RNE float->bf16 for FINITE values: bf16 bits land in the high 16.
static __device__ __forceinline__ unsigned bfbits(float f) {
  unsigned u = __float_as_uint(f);
  return u + 0x7fffu + ((u >> 16) & 1u);
}
static __device__ __forceinline__ unsigned short f2bf(float f) {
  return (unsigned short)(bfbits(f) >> 16);
}
// RNE pack of two floats to packed bf16x2 (lo in low half).
static __device__ __forceinline__ unsigned pack2bf(float lo, float hi) {
  return __builtin_amdgcn_perm(bfbits(hi), bfbits(lo), 0x07060302u);
}
// Truncation pack (round-toward-zero for positives): 1 v_perm on raw bits.
static __device__ __forceinline__ unsigned pack2tr(unsigned ulo, unsigned uhi) {
  return __builtin_amdgcn_perm(uhi, ulo, 0x07060302u);
}

typedef const __attribute__((address_space(1))) unsigned int* gp_t;
typedef __attribute__((address_space(3))) unsigned int* lp_t;
static __device__ __forceinline__ void gload_lds16(const void* g, void* l) {
  __builtin_amdgcn_global_load_lds((gp_t)g, (lp_t)l, 16, 0, 0);
}

// ---------------------------------------------------------------------------
// x fp32 -> bf16 cast (8 elems/thread).
// ---------------------------------------------------------------------------
__global__ __launch_bounds__(256) void xcast(const float* __restrict__ x,
                                             unsigned short* __restrict__ xb) {
  size_t i = ((size_t)blockIdx.x * 256 + threadIdx.x) * 8;
  f32x4 a = *(const f32x4*)&x[i];
  f32x4 b = *(const f32x4*)&x[i + 4];
  uint4v s;
  s[0] = pack2bf(a[0], a[1]);
  s[1] = pack2bf(a[2], a[3]);
  s[2] = pack2bf(b[0], b[1]);
  s[3] = pack2bf(b[2], b[3]);
  *(uint4v*)&xb[i] = s;
}

// ---------------------------------------------------------------------------
// Weight transpose: W [K][N] fp32 -> WT [N][K] bf16. 64x64 tiles, 256 thr.
// ---------------------------------------------------------------------------
__global__ __launch_bounds__(256) void transpose_w(
    const float* __restrict__ W, unsigned short* __restrict__ WT, int K, int N) {
  __shared__ float T[64][65];
  const int tid = threadIdx.x;
  const int n0 = blockIdx.x * 64;
  const int k0 = blockIdx.y * 64;
#pragma unroll
  for (int it = 0; it < 4; it++) {
    int row = it * 16 + (tid >> 4);
    int c4 = (tid & 15) * 4;
    f32x4 v = *(const f32x4*)&W[(size_t)(k0 + row) * N + n0 + c4];
#pragma unroll
    for (int j = 0; j < 4; j++) T[row][c4 + j] = v[j];
  }
  __syncthreads();
#pragma unroll
  for (int it = 0; it < 2; it++) {
    int chunk = tid + it * 256;
    int n = chunk >> 3;
    int c8 = (chunk & 7) * 8;
    uint4v s;
#pragma unroll
    for (int j = 0; j < 4; j++)
      s[j] = pack2bf(T[c8 + 2 * j][n], T[c8 + 2 * j + 1][n]);
    *(uint4v*)&WT[(size_t)(n0 + n) * K + k0 + c8] = s;
  }
}

// ---------------------------------------------------------------------------
// GEMM: C[M,N] = A[M,K] @ BT[N,K]^T, fp32 accum. 128x128 tile, BK=64,
// 256 threads (4 waves 2x2). Tiles stored with granule-XOR swizzle:
// LDS[r][g] holds global granule (g ^ (r&7)) of row r (granule = 8 shorts).
// -> conflict-free b128 fragment reads; DMA staging swizzles the SOURCE.
// MODE 0: A fp32 (VALU cvt staging); QKV scatter epilogue (V transposed).
// MODE 2: A bf16 (DMA staging);      QKV scatter epilogue (V transposed).
// MODE 1: A bf16 (DMA staging);      fp32 row-major output.
// ---------------------------------------------------------------------------
template <int MODE>
__global__ __launch_bounds__(256) void gemm_kernel(
    const void* __restrict__ Av, const unsigned short* __restrict__ BT,
    unsigned short* __restrict__ out0, unsigned short* __restrict__ out1,
    unsigned short* __restrict__ out2, float* __restrict__ outf,
    int M, int N, int K) {
  __shared__ unsigned short As[128][64];
  __shared__ unsigned short Bs[128][64];

  const int tid = threadIdx.x;
  const int wave = tid >> 6;
  const int lane = tid & 63;
  const int quad = lane >> 4;
  const int lc = lane & 15;
  const int wr = wave >> 1;
  const int wc = wave & 1;
  const int m0 = blockIdx.y * 128;
  const int n0 = blockIdx.x * 128;
  const int xsw = lc & 7;               // fragment-read swizzle key
  const int lr8 = lane >> 3;            // staging: row within 8-row group
  const int sgo = ((lane & 7) ^ (lr8 & 7)) * 8;  // swizzled source offset

  f32x4 acc[4][4];
#pragma unroll
  for (int i = 0; i < 4; i++)
#pragma unroll
    for (int j = 0; j < 4; j++) acc[i][j] = (f32x4){0.f, 0.f, 0.f, 0.f};

  for (int k0 = 0; k0 < K; k0 += 64) {
    // ---- Stage A tile (128 x 64) ----
    if (MODE == 0) {
      const float* A = (const float*)Av;
#pragma unroll
      for (int i = 0; i < 4; i++) {
        int chunk = tid + i * 256;      // 1024 granules
        int r = chunk >> 3;
        int g = chunk & 7;
        int scol = (g ^ (r & 7)) * 8;
        f32x4 v0 = *(const f32x4*)&A[(size_t)(m0 + r) * K + k0 + scol];
        f32x4 v1 = *(const f32x4*)&A[(size_t)(m0 + r) * K + k0 + scol + 4];
        uint4v s;
        s[0] = pack2bf(v0[0], v0[1]);
        s[1] = pack2bf(v0[2], v0[3]);
        s[2] = pack2bf(v1[0], v1[1]);
        s[3] = pack2bf(v1[2], v1[3]);
        *(uint4v*)&As[r][g * 8] = s;
      }
    } else {
      const unsigned short* A = (const unsigned short*)Av;
#pragma unroll
      for (int it = 0; it < 4; it++) {
        int rbase = wave * 32 + it * 8;  // 8 rows = 1 KB per instruction
        gload_lds16(&A[(size_t)(m0 + rbase + lr8) * K + k0 + sgo],
                    &As[rbase][0]);
      }
    }
    // ---- Stage B tile (128 n-rows x 64 k) ----
#pragma unroll
    for (int it = 0; it < 4; it++) {
      int rbase = wave * 32 + it * 8;
      gload_lds16(&BT[(size_t)(n0 + rbase + lr8) * K + k0 + sgo],
                  &Bs[rbase][0]);
    }
    __syncthreads();

#pragma unroll
    for (int kc = 0; kc < 2; kc++) {
      short8 aA[4], bB[4];
#pragma unroll
      for (int mt = 0; mt < 4; mt++)
        aA[mt] = *(const short8*)&As[wr * 64 + mt * 16 + lc]
                                    [((kc * 4 + quad) ^ xsw) * 8];
#pragma unroll
      for (int nt = 0; nt < 4; nt++)
        bB[nt] = *(const short8*)&Bs[wc * 64 + nt * 16 + lc]
                                    [((kc * 4 + quad) ^ xsw) * 8];
#pragma unroll
      for (int mt = 0; mt < 4; mt++)
#pragma unroll
        for (int nt = 0; nt < 4; nt++)
          acc[mt][nt] = __builtin_amdgcn_mfma_f32_16x16x32_bf16(
              aA[mt], bB[nt], acc[mt][nt], 0, 0, 0);
    }
    __syncthreads();
  }

  // Epilogue: C/D layout col=lane&15, row=quad*4+reg.
  const int c = n0 >> 10;  // QKV segment (block-uniform): 0=Q 1=K 2=V
#pragma unroll
  for (int mt = 0; mt < 4; mt++)
#pragma unroll
    for (int nt = 0; nt < 4; nt++) {
      int rb = m0 + wr * 64 + mt * 16 + quad * 4;  // 4 consecutive tokens
      int col = n0 + wc * 64 + nt * 16 + lc;
      if (MODE == 1) {
#pragma unroll
        for (int r = 0; r < 4; r++)
          outf[(size_t)(rb + r) * N + col] = acc[mt][nt][r];
      } else {
        int rem = col & 1023;
        int h = rem >> 6;
        int dd = rem & 63;
        int b = rb >> 11;
        int tt = rb & 2047;
        if (c == 2) {
          uint2v pk;
          pk[0] = pack2bf(acc[mt][nt][0], acc[mt][nt][1]);
          pk[1] = pack2bf(acc[mt][nt][2], acc[mt][nt][3]);
          *(uint2v*)&out2[(((size_t)(b * NH + h)) * DH + dd) * SEQ + tt] = pk;
        } else {
          unsigned short* dst = (c == 0) ? out0 : out1;
          float sc = (c == 0) ? QSCALE : 1.0f;
#pragma unroll
          for (int r = 0; r < 4; r++)
            dst[(((size_t)(b * NH + h) * SEQ + tt + r) << 6) + dd] =
                f2bf(acc[mt][nt][r] * sc);
        }
      }
    }
}

// ---------------------------------------------------------------------------
// Flash attention. Q,K: [bh][T][64] bf16 (Q pre-scaled); Vt: [bh][64][T] bf16.
// Block = 256 thr = 4 waves; wave owns 32 q-rows (block 128); 64-key tiles.
// S^T = K·Q^T via 32x32x16 MFMA -> 4 consecutive keys per lane. P packed by
// TRUNCATION (1 v_perm / pair); P half-exchange in-register via
// v_permlane32_swap_b32. K/Vt double-buffered (stage t+1, compute t).
// NEW vs prev round (VALU-bound diagnosis: VALUBusy 58%, MfmaUtil 27%):
//  * l computed by MFMA ride-along: o_l = P·ones accumulated with the SAME
//    truncated P fragments as PV -> removes 32 VALU ops/tile (truncate+add)
//    and the entire lbuf/shfl/syncthreads epilogue. o_l rows align with o.
//  * persistent zero f32x16 as C-input of each S chain head -> removes 32
//    zero-init movs/tile.
//  * XCD-aware 1D grid swizzle: each XCD owns 8 whole heads -> K/V L2-local
//    (FETCH_SIZE predicted 139 MB -> ~60 MB).
// ---------------------------------------------------------------------------
__global__ __launch_bounds__(256) void attn_kernel(
    const unsigned short* __restrict__ Q, const unsigned short* __restrict__ K,
    const unsigned short* __restrict__ Vt, unsigned short* __restrict__ ctx) {
  __shared__ unsigned short KsL[2][64 * 64];  // granule-swizzled [key][d]
  __shared__ unsigned short VtL[2][64 * 64];  // granule-swizzled [d][key]

  const int tid = threadIdx.x;
  const int wave = tid >> 6;
  const int lane = tid & 63;
  const int half = lane >> 5;
  const int l31 = lane & 31;
  // XCD swizzle: dispatch order round-robins XCDs (id%8). Give each XCD 8
  // consecutive heads so all 16 q-tiles of a head share one L2.
  const int id = blockIdx.x;
  const int bh = (id & 7) * 8 + (id >> 3) / 16;
  const int qt = (id >> 3) & 15;
  const int q0 = qt * 128 + wave * 32;
  const size_t kqbase = (size_t)bh * SEQ * DH;
  const size_t vbase = (size_t)bh * DH * SEQ;

  // Q B-fragments (n=qrow=l31, k=d): 4 d-chunks of 16.
  short8 bQ[4];
#pragma unroll
  for (int dc = 0; dc < 4; dc++)
    bQ[dc] = *(const short8*)&Q[kqbase + (size_t)(q0 + l31) * DH + dc * 16 + half * 8];

  f32x16 o[2], o_l;
#pragma unroll
  for (int nb = 0; nb < 2; nb++)
#pragma unroll
    for (int j = 0; j < 16; j++) o[nb][j] = 0.f;
#pragma unroll
  for (int j = 0; j < 16; j++) o_l[j] = 0.f;

  // Persistent zero C-input for S chains (parked in 16 VGPRs, never written).
  f32x16 zf;
#pragma unroll
  for (int j = 0; j < 16; j++) zf[j] = 0.f;

  // All-ones bf16 B fragment for the l ride-along MFMA.
  union { unsigned u[4]; short8 s8; } onesu;
#pragma unroll
  for (int j = 0; j < 4; j++) onesu.u[j] = 0x3f803f80u;
  const short8 ones = onesu.s8;

  const int xsw = l31 & 7;  // bank-swizzle key for this lane's fragment rows
  // Hoisted staging geometry (granule id = wave*128 + it*64 + lane).
  const int g0 = wave * 128 + lane;
  const int r0 = g0 >> 3, r1 = (g0 + 64) >> 3;
  const size_t so0 = (size_t)r0 * DH + (((g0 & 7) ^ (r0 & 7)) * 8);
  const size_t so1 = (size_t)r1 * DH + (((g0 & 7) ^ (r1 & 7)) * 8);
  const size_t sv0 = (size_t)r0 * SEQ + (((g0 & 7) ^ (r0 & 7)) * 8);
  const size_t sv1 = (size_t)r1 * SEQ + (((g0 & 7) ^ (r1 & 7)) * 8);
  const int ldo = wave * 1024;  // this wave's staging region (shorts)

  auto stage = [&](int kt, int b) {
    const size_t kg = kqbase + (size_t)kt * 64 * DH;
    const size_t vg = vbase + (size_t)kt * 64;
    unsigned short* kd = &KsL[b][ldo];
    unsigned short* vd = &VtL[b][ldo];
    gload_lds16(&K[kg + so0], kd);
    gload_lds16(&K[kg + so1], kd + 512);
    gload_lds16(&Vt[vg + sv0], vd);
    gload_lds16(&Vt[vg + sv1], vd + 512);
  };

  stage(0, 0);
  __syncthreads();

  for (int kt = 0; kt < SEQ / 64; kt++) {
    const int cur = kt & 1;
    if (kt + 1 < SEQ / 64) stage(kt + 1, cur ^ 1);  // prefetch next tile
    const unsigned short* kcur = &KsL[cur][0];
    const unsigned short* vcur = &VtL[cur][0];

    // S^T = K·Q^T : two 32-key blocks, contraction d=64 (4 chained MFMA),
    // then softmax+pack and P·V for that key-block (in-register exchange).
#pragma unroll
    for (int kb = 0; kb < 2; kb++) {
      __builtin_amdgcn_s_setprio(1);
      f32x16 s = zf;
#pragma unroll
      for (int dc = 0; dc < 4; dc++) {
        const short8 aK = *(const short8*)&kcur[(size_t)(kb * 32 + l31) * 64 +
                                                ((dc * 2 + half) ^ xsw) * 8];
        s = __builtin_amdgcn_mfma_f32_32x32x16_bf16(aK, bQ[dc], s, 0, 0, 0);
      }
      __builtin_amdgcn_s_setprio(0);

      // p = exp2(s); truncate to bf16 (pack is 1 v_perm per pair).
      // Lane (l31,half) holds keys kb*32 + gq*8 + half*4 + {0..3} as packed
      // dwords d0[gq] (keys +0,1) and d1[gq] (keys +2,3).
      unsigned d0[4], d1[4];
#pragma unroll
      for (int gq = 0; gq < 4; gq++) {
        unsigned u0 = __float_as_uint(__builtin_amdgcn_exp2f(s[gq * 4 + 0]));
        unsigned u1 = __float_as_uint(__builtin_amdgcn_exp2f(s[gq * 4 + 1]));
        unsigned u2 = __float_as_uint(__builtin_amdgcn_exp2f(s[gq * 4 + 2]));
        unsigned u3 = __float_as_uint(__builtin_amdgcn_exp2f(s[gq * 4 + 3]));
        d0[gq] = pack2tr(u0, u1);
        d1[gq] = pack2tr(u2, u3);
      }

      // O += P·V for this 32-key block: chunks kc = kb*2 + {0,1}.
      // A-fragment dwords for chunk: w0..w3 = keys chunk*16 + half*8 + pairs.
      // v_permlane32_swap_b32 exchanges a.hi-lanes with b.lo-lanes:
      //   swap(d0[2k], d0[2k+1]) -> (w0, w2); swap(d1[2k], d1[2k+1]) -> (w1, w3).
      // l rides along as o_l = P·ones (same A fragments, same truncation ->
      // exactly self-consistent normalization, zero VALU cost).
#pragma unroll
      for (int kcl = 0; kcl < 2; kcl++) {
        unsigned w0 = d0[kcl * 2], w2 = d0[kcl * 2 + 1];
        unsigned w1 = d1[kcl * 2], w3 = d1[kcl * 2 + 1];
        asm("v_permlane32_swap_b32 %0, %1" : "+v"(w0), "+v"(w2));
        asm("v_permlane32_swap_b32 %0, %1" : "+v"(w1), "+v"(w3));
        union { unsigned u[4]; short8 s8; } cv;
        cv.u[0] = w0; cv.u[1] = w1; cv.u[2] = w2; cv.u[3] = w3;
        const int kc = kb * 2 + kcl;
        __builtin_amdgcn_s_setprio(1);
#pragma unroll
        for (int nb = 0; nb < 2; nb++) {
          const short8 bV = *(const short8*)&vcur[(size_t)(nb * 32 + l31) * 64 +
                                                  ((kc * 2 + half) ^ xsw) * 8];
          o[nb] = __builtin_amdgcn_mfma_f32_32x32x16_bf16(cv.s8, bV, o[nb], 0, 0, 0);
        }
        o_l = __builtin_amdgcn_mfma_f32_32x32x16_bf16(cv.s8, ones, o_l, 0, 0, 0);
        __builtin_amdgcn_s_setprio(0);
      }
    }
    __syncthreads();  // staged next tile complete; buffers free for overwrite
  }

  // Epilogue: o_l rows align with o rows (same A-op, same MFMA shape), so
  // normalization is purely lane-local. ctx write coalesced over l31.
  const int b = bh >> 4;
  const int h = bh & 15;
#pragma unroll
  for (int gq = 0; gq < 4; gq++)
#pragma unroll
    for (int j = 0; j < 4; j++) {
      int r = gq * 4 + j;
      int ql = j + gq * 8 + half * 4;  // q within wave (C-layout row)
      float inv = __builtin_amdgcn_rcpf(o_l[r]);
      int token = qt * 128 + wave * 32 + ql;
#pragma unroll
      for (int nb = 0; nb < 2; nb++)
        ctx[((size_t)b * SEQ + token) * DM + h * DH + nb * 32 + l31] =
            f2bf(o[nb][r] * inv);
    }
}

extern "C" void kernel_launch(void* const* d_in, const int* in_sizes, int n_in,
                              void* d_out, int out_size, void* d_ws,
                              size_t ws_size, hipStream_t stream) {
  const float* x = (const float*)d_in[0];     // [8192,1024] fp32
  const float* Wqkv = (const float*)d_in[1];  // [1024,3072] fp32
  const float* Wo = (const float*)d_in[2];    // [1024,1024] fp32
  float* out = (float*)d_out;                 // [8192,1024] fp32
  unsigned short* ws = (unsigned short*)d_ws;

  unsigned short* Qb = ws;                          // [bh][T][64], pre-scaled
  unsigned short* Kb = ws + SEG;                    // [bh][T][64]
  unsigned short* Vt = ws + 2 * SEG;                // [bh][64][T]
  unsigned short* Ctx = ws + 3 * SEG;               // [8192][1024]
  unsigned short* WqT = Ctx + (size_t)MTOK * DM;    // [3072][1024]
  unsigned short* WoT = WqT + (size_t)3 * DM * DM;  // [1024][1024]
  unsigned short* Xb = WoT + (size_t)DM * DM;       // [8192][1024]
  const size_t need =
      ((size_t)(Xb - ws) + (size_t)MTOK * DM) * sizeof(unsigned short);

  transpose_w<<<dim3(3 * DM / 64, DM / 64), 256, 0, stream>>>(Wqkv, WqT, DM, 3 * DM);
  transpose_w<<<dim3(DM / 64, DM / 64), 256, 0, stream>>>(Wo, WoT, DM, DM);

  if (ws_size >= need) {
    xcast<<<(MTOK * DM) / (256 * 8), 256, 0, stream>>>(x, Xb);
    gemm_kernel<2><<<dim3(3 * DM / 128, MTOK / 128), 256, 0, stream>>>(
        (const void*)Xb, WqT, Qb, Kb, Vt, nullptr, MTOK, 3 * DM, DM);
  } else {
    gemm_kernel<0><<<dim3(3 * DM / 128, MTOK / 128), 256, 0, stream>>>(
        (const void*)x, WqT, Qb, Kb, Vt, nullptr, MTOK, 3 * DM, DM);
  }
  attn_kernel<<<dim3(SEQ / 128 * NBATCH * NH), 256, 0, stream>>>(Qb, Kb, Vt, Ctx);
  gemm_kernel<1><<<dim3(DM / 128, MTOK / 128), 256, 0, stream>>>(
      (const void*)Ctx, WoT, nullptr, nullptr, nullptr, out, MTOK, DM, DM);
}

// Round 3
// 260.199 us; speedup vs baseline: 1.1105x; 1.0905x over previous
//
#include <hip/hip_runtime.h>
#include <hip/hip_bf16.h>

typedef __attribute__((ext_vector_type(8))) short short8;
typedef __attribute__((ext_vector_type(4))) float f32x4;
typedef __attribute__((ext_vector_type(16))) float f32x16;
typedef __attribute__((ext_vector_type(2))) unsigned int uint2v;
typedef __attribute__((ext_vector_type(4))) unsigned int uint4v;

#define SEQ    2048
#define DM     1024
#define NH     16
#define DH     64
#define NBATCH 4
#define MTOK   (NBATCH * SEQ)                       // 8192 tokens
#define SEG    ((size_t)NBATCH * NH * SEQ * DH)     // 8388608 elems per Q/K/V buffer
// Q pre-scaled by 1/sqrt(64) * log2(e) so attention inner loop is exp2 only.
#define QSCALE 0.18033688f

// Fast RNE float->bf16 for FINITE values: bf16 bits land in the high 16.
static __device__ __forceinline__ unsigned bfbits(float f) {
  unsigned u = __float_as_uint(f);
  return u + 0x7fffu + ((u >> 16) & 1u);
}
static __device__ __forceinline__ unsigned short f2bf(float f) {
  return (unsigned short)(bfbits(f) >> 16);
}
// RNE pack of two floats to packed bf16x2 (lo in low half).
static __device__ __forceinline__ unsigned pack2bf(float lo, float hi) {
  return __builtin_amdgcn_perm(bfbits(hi), bfbits(lo), 0x07060302u);
}
// Truncation pack (round-toward-zero for positives): 1 v_perm on raw bits.
static __device__ __forceinline__ unsigned pack2tr(unsigned ulo, unsigned uhi) {
  return __builtin_amdgcn_perm(uhi, ulo, 0x07060302u);
}

typedef const __attribute__((address_space(1))) unsigned int* gp_t;
typedef __attribute__((address_space(3))) unsigned int* lp_t;
static __device__ __forceinline__ void gload_lds16(const void* g, void* l) {
  __builtin_amdgcn_global_load_lds((gp_t)g, (lp_t)l, 16, 0, 0);
}

// ---------------------------------------------------------------------------
// x fp32 -> bf16 cast (8 elems/thread).
// ---------------------------------------------------------------------------
__global__ __launch_bounds__(256) void xcast(const float* __restrict__ x,
                                             unsigned short* __restrict__ xb) {
  size_t i = ((size_t)blockIdx.x * 256 + threadIdx.x) * 8;
  f32x4 a = *(const f32x4*)&x[i];
  f32x4 b = *(const f32x4*)&x[i + 4];
  uint4v s;
  s[0] = pack2bf(a[0], a[1]);
  s[1] = pack2bf(a[2], a[3]);
  s[2] = pack2bf(b[0], b[1]);
  s[3] = pack2bf(b[2], b[3]);
  *(uint4v*)&xb[i] = s;
}

// ---------------------------------------------------------------------------
// Weight transpose: W [K][N] fp32 -> WT [N][K] bf16. 64x64 tiles, 256 thr.
// ---------------------------------------------------------------------------
__global__ __launch_bounds__(256) void transpose_w(
    const float* __restrict__ W, unsigned short* __restrict__ WT, int K, int N) {
  __shared__ float T[64][65];
  const int tid = threadIdx.x;
  const int n0 = blockIdx.x * 64;
  const int k0 = blockIdx.y * 64;
#pragma unroll
  for (int it = 0; it < 4; it++) {
    int row = it * 16 + (tid >> 4);
    int c4 = (tid & 15) * 4;
    f32x4 v = *(const f32x4*)&W[(size_t)(k0 + row) * N + n0 + c4];
#pragma unroll
    for (int j = 0; j < 4; j++) T[row][c4 + j] = v[j];
  }
  __syncthreads();
#pragma unroll
  for (int it = 0; it < 2; it++) {
    int chunk = tid + it * 256;
    int n = chunk >> 3;
    int c8 = (chunk & 7) * 8;
    uint4v s;
#pragma unroll
    for (int j = 0; j < 4; j++)
      s[j] = pack2bf(T[c8 + 2 * j][n], T[c8 + 2 * j + 1][n]);
    *(uint4v*)&WT[(size_t)(n0 + n) * K + k0 + c8] = s;
  }
}

// ---------------------------------------------------------------------------
// GEMM: C[M,N] = A[M,K] @ BT[N,K]^T, fp32 accum. 128x128 tile, BK=64,
// 256 threads (4 waves 2x2). Tiles stored with granule-XOR swizzle:
// LDS[r][g] holds global granule (g ^ (r&7)) of row r (granule = 8 shorts).
// -> conflict-free b128 fragment reads; DMA staging swizzles the SOURCE.
// MODE 0: A fp32 (VALU cvt staging); QKV scatter epilogue (V transposed).
// MODE 2: A bf16 (DMA staging);      QKV scatter epilogue (V transposed).
// MODE 1: A bf16 (DMA staging);      fp32 row-major output.
// ---------------------------------------------------------------------------
template <int MODE>
__global__ __launch_bounds__(256) void gemm_kernel(
    const void* __restrict__ Av, const unsigned short* __restrict__ BT,
    unsigned short* __restrict__ out0, unsigned short* __restrict__ out1,
    unsigned short* __restrict__ out2, float* __restrict__ outf,
    int M, int N, int K) {
  __shared__ unsigned short As[128][64];
  __shared__ unsigned short Bs[128][64];

  const int tid = threadIdx.x;
  const int wave = tid >> 6;
  const int lane = tid & 63;
  const int quad = lane >> 4;
  const int lc = lane & 15;
  const int wr = wave >> 1;
  const int wc = wave & 1;
  const int m0 = blockIdx.y * 128;
  const int n0 = blockIdx.x * 128;
  const int xsw = lc & 7;               // fragment-read swizzle key
  const int lr8 = lane >> 3;            // staging: row within 8-row group
  const int sgo = ((lane & 7) ^ (lr8 & 7)) * 8;  // swizzled source offset

  f32x4 acc[4][4];
#pragma unroll
  for (int i = 0; i < 4; i++)
#pragma unroll
    for (int j = 0; j < 4; j++) acc[i][j] = (f32x4){0.f, 0.f, 0.f, 0.f};

  for (int k0 = 0; k0 < K; k0 += 64) {
    // ---- Stage A tile (128 x 64) ----
    if (MODE == 0) {
      const float* A = (const float*)Av;
#pragma unroll
      for (int i = 0; i < 4; i++) {
        int chunk = tid + i * 256;      // 1024 granules
        int r = chunk >> 3;
        int g = chunk & 7;
        int scol = (g ^ (r & 7)) * 8;
        f32x4 v0 = *(const f32x4*)&A[(size_t)(m0 + r) * K + k0 + scol];
        f32x4 v1 = *(const f32x4*)&A[(size_t)(m0 + r) * K + k0 + scol + 4];
        uint4v s;
        s[0] = pack2bf(v0[0], v0[1]);
        s[1] = pack2bf(v0[2], v0[3]);
        s[2] = pack2bf(v1[0], v1[1]);
        s[3] = pack2bf(v1[2], v1[3]);
        *(uint4v*)&As[r][g * 8] = s;
      }
    } else {
      const unsigned short* A = (const unsigned short*)Av;
#pragma unroll
      for (int it = 0; it < 4; it++) {
        int rbase = wave * 32 + it * 8;  // 8 rows = 1 KB per instruction
        gload_lds16(&A[(size_t)(m0 + rbase + lr8) * K + k0 + sgo],
                    &As[rbase][0]);
      }
    }
    // ---- Stage B tile (128 n-rows x 64 k) ----
#pragma unroll
    for (int it = 0; it < 4; it++) {
      int rbase = wave * 32 + it * 8;
      gload_lds16(&BT[(size_t)(n0 + rbase + lr8) * K + k0 + sgo],
                  &Bs[rbase][0]);
    }
    __syncthreads();

#pragma unroll
    for (int kc = 0; kc < 2; kc++) {
      short8 aA[4], bB[4];
#pragma unroll
      for (int mt = 0; mt < 4; mt++)
        aA[mt] = *(const short8*)&As[wr * 64 + mt * 16 + lc]
                                    [((kc * 4 + quad) ^ xsw) * 8];
#pragma unroll
      for (int nt = 0; nt < 4; nt++)
        bB[nt] = *(const short8*)&Bs[wc * 64 + nt * 16 + lc]
                                    [((kc * 4 + quad) ^ xsw) * 8];
#pragma unroll
      for (int mt = 0; mt < 4; mt++)
#pragma unroll
        for (int nt = 0; nt < 4; nt++)
          acc[mt][nt] = __builtin_amdgcn_mfma_f32_16x16x32_bf16(
              aA[mt], bB[nt], acc[mt][nt], 0, 0, 0);
    }
    __syncthreads();
  }

  // Epilogue: C/D layout col=lane&15, row=quad*4+reg.
  const int c = n0 >> 10;  // QKV segment (block-uniform): 0=Q 1=K 2=V
#pragma unroll
  for (int mt = 0; mt < 4; mt++)
#pragma unroll
    for (int nt = 0; nt < 4; nt++) {
      int rb = m0 + wr * 64 + mt * 16 + quad * 4;  // 4 consecutive tokens
      int col = n0 + wc * 64 + nt * 16 + lc;
      if (MODE == 1) {
#pragma unroll
        for (int r = 0; r < 4; r++)
          outf[(size_t)(rb + r) * N + col] = acc[mt][nt][r];
      } else {
        int rem = col & 1023;
        int h = rem >> 6;
        int dd = rem & 63;
        int b = rb >> 11;
        int tt = rb & 2047;
        if (c == 2) {
          uint2v pk;
          pk[0] = pack2bf(acc[mt][nt][0], acc[mt][nt][1]);
          pk[1] = pack2bf(acc[mt][nt][2], acc[mt][nt][3]);
          *(uint2v*)&out2[(((size_t)(b * NH + h)) * DH + dd) * SEQ + tt] = pk;
        } else {
          unsigned short* dst = (c == 0) ? out0 : out1;
          float sc = (c == 0) ? QSCALE : 1.0f;
#pragma unroll
          for (int r = 0; r < 4; r++)
            dst[(((size_t)(b * NH + h) * SEQ + tt + r) << 6) + dd] =
                f2bf(acc[mt][nt][r] * sc);
        }
      }
    }
}

// ---------------------------------------------------------------------------
// Flash attention. Q,K: [bh][T][64] bf16 (Q pre-scaled); Vt: [bh][64][T] bf16.
// Block = 256 thr = 4 waves; wave owns 32 q-rows (block 128); 64-key tiles.
// S^T = K·Q^T via 32x32x16 MFMA -> 4 consecutive keys per lane. P packed by
// TRUNCATION; half-exchange via v_permlane32_swap_b32; l via MFMA ride-along
// (o_l = P·ones, same truncated fragments -> self-consistent). K/Vt
// double-buffered; XCD-aware grid (each XCD owns 8 heads; FETCH 24.6 MB).
// NEW vs prev round (latency-bound diagnosis: all pipes <50%, occ 24%):
//  * Register diet to get back under the 64-VGPR allocation step (round 1:
//    64 VGPR -> 32% occ; round 2: 72 VGPR -> 24% occ): zf dropped, staging
//    offsets 32-bit with so1/sv1 derived by constant add.
//  * __launch_bounds__(256, 4): request 4 waves/EU (4 blocks/CU; LDS
//    4x32KB=128KB fits) so the per-tile dependent chains (QK MFMA chain ->
//    exp2 -> pack -> PV chain) are hidden by 4-way TLP instead of 2-way.
// ---------------------------------------------------------------------------
__global__ __launch_bounds__(256, 4) void attn_kernel(
    const unsigned short* __restrict__ Q, const unsigned short* __restrict__ K,
    const unsigned short* __restrict__ Vt, unsigned short* __restrict__ ctx) {
  __shared__ unsigned short KsL[2][64 * 64];  // granule-swizzled [key][d]
  __shared__ unsigned short VtL[2][64 * 64];  // granule-swizzled [d][key]

  const int tid = threadIdx.x;
  const int wave = tid >> 6;
  const int lane = tid & 63;
  const int half = lane >> 5;
  const int l31 = lane & 31;
  // XCD swizzle: dispatch order round-robins XCDs (id%8). Give each XCD 8
  // consecutive heads so all 16 q-tiles of a head share one L2.
  const int id = blockIdx.x;
  const int bh = (id & 7) * 8 + (id >> 3) / 16;
  const int qt = (id >> 3) & 15;
  const int q0 = qt * 128 + wave * 32;
  const unsigned kqbase = (unsigned)bh * (SEQ * DH);  // offsets fit 32-bit
  const unsigned vbase = (unsigned)bh * (DH * SEQ);

  // Q B-fragments (n=qrow=l31, k=d): 4 d-chunks of 16.
  short8 bQ[4];
#pragma unroll
  for (int dc = 0; dc < 4; dc++)
    bQ[dc] = *(const short8*)&Q[kqbase + (unsigned)(q0 + l31) * DH + dc * 16 + half * 8];

  f32x16 o[2], o_l;
#pragma unroll
  for (int nb = 0; nb < 2; nb++)
#pragma unroll
    for (int j = 0; j < 16; j++) o[nb][j] = 0.f;
#pragma unroll
  for (int j = 0; j < 16; j++) o_l[j] = 0.f;

  // All-ones bf16 B fragment for the l ride-along MFMA.
  union { unsigned u[4]; short8 s8; } onesu;
#pragma unroll
  for (int j = 0; j < 4; j++) onesu.u[j] = 0x3f803f80u;
  const short8 ones = onesu.s8;

  const int xsw = l31 & 7;  // bank-swizzle key for this lane's fragment rows
  // Hoisted staging geometry (granule id = wave*128 + it*64 + lane).
  // Second issue of each pair is +8 rows: same swizzle ((g0+64)&7 == g0&7,
  // (r0+8)&7 == r0&7) -> derive by constant add, no extra registers.
  const int g0 = wave * 128 + lane;
  const int r0 = g0 >> 3;
  const unsigned sgo = ((g0 & 7) ^ (r0 & 7)) * 8;
  const unsigned so0 = (unsigned)r0 * DH + sgo;
  const unsigned sv0 = (unsigned)r0 * SEQ + sgo;
  const int ldo = wave * 1024;  // this wave's staging region (shorts)

  auto stage = [&](int kt, int b) {
    const unsigned kg = kqbase + (unsigned)kt * (64 * DH);
    const unsigned vg = vbase + (unsigned)kt * 64;
    unsigned short* kd = &KsL[b][ldo];
    unsigned short* vd = &VtL[b][ldo];
    gload_lds16(&K[kg + so0], kd);
    gload_lds16(&K[kg + so0 + 8 * DH], kd + 512);
    gload_lds16(&Vt[vg + sv0], vd);
    gload_lds16(&Vt[vg + sv0 + 8 * SEQ], vd + 512);
  };

  stage(0, 0);
  __syncthreads();

  for (int kt = 0; kt < SEQ / 64; kt++) {
    const int cur = kt & 1;
    if (kt + 1 < SEQ / 64) stage(kt + 1, cur ^ 1);  // prefetch next tile
    const unsigned short* kcur = &KsL[cur][0];
    const unsigned short* vcur = &VtL[cur][0];

    // S^T = K·Q^T : two 32-key blocks, contraction d=64 (4 chained MFMA),
    // then softmax+pack and P·V for that key-block (in-register exchange).
#pragma unroll
    for (int kb = 0; kb < 2; kb++) {
      f32x16 s;
#pragma unroll
      for (int j = 0; j < 16; j++) s[j] = 0.f;
      __builtin_amdgcn_s_setprio(1);
#pragma unroll
      for (int dc = 0; dc < 4; dc++) {
        const short8 aK = *(const short8*)&kcur[(unsigned)(kb * 32 + l31) * 64 +
                                                ((dc * 2 + half) ^ xsw) * 8];
        s = __builtin_amdgcn_mfma_f32_32x32x16_bf16(aK, bQ[dc], s, 0, 0, 0);
      }
      __builtin_amdgcn_s_setprio(0);

      // p = exp2(s); truncate to bf16 (pack is 1 v_perm per pair).
      // Lane (l31,half) holds keys kb*32 + gq*8 + half*4 + {0..3} as packed
      // dwords d0[gq] (keys +0,1) and d1[gq] (keys +2,3).
      unsigned d0[4], d1[4];
#pragma unroll
      for (int gq = 0; gq < 4; gq++) {
        unsigned u0 = __float_as_uint(__builtin_amdgcn_exp2f(s[gq * 4 + 0]));
        unsigned u1 = __float_as_uint(__builtin_amdgcn_exp2f(s[gq * 4 + 1]));
        unsigned u2 = __float_as_uint(__builtin_amdgcn_exp2f(s[gq * 4 + 2]));
        unsigned u3 = __float_as_uint(__builtin_amdgcn_exp2f(s[gq * 4 + 3]));
        d0[gq] = pack2tr(u0, u1);
        d1[gq] = pack2tr(u2, u3);
      }

      // O += P·V for this 32-key block: chunks kc = kb*2 + {0,1}.
      // A-fragment dwords for chunk: w0..w3 = keys chunk*16 + half*8 + pairs.
      // v_permlane32_swap_b32 exchanges a.hi-lanes with b.lo-lanes:
      //   swap(d0[2k], d0[2k+1]) -> (w0, w2); swap(d1[2k], d1[2k+1]) -> (w1, w3).
      // l rides along as o_l = P·ones (same A fragments, same truncation ->
      // exactly self-consistent normalization, zero VALU cost).
#pragma unroll
      for (int kcl = 0; kcl < 2; kcl++) {
        unsigned w0 = d0[kcl * 2], w2 = d0[kcl * 2 + 1];
        unsigned w1 = d1[kcl * 2], w3 = d1[kcl * 2 + 1];
        asm("v_permlane32_swap_b32 %0, %1" : "+v"(w0), "+v"(w2));
        asm("v_permlane32_swap_b32 %0, %1" : "+v"(w1), "+v"(w3));
        union { unsigned u[4]; short8 s8; } cv;
        cv.u[0] = w0; cv.u[1] = w1; cv.u[2] = w2; cv.u[3] = w3;
        const int kc = kb * 2 + kcl;
        __builtin_amdgcn_s_setprio(1);
#pragma unroll
        for (int nb = 0; nb < 2; nb++) {
          const short8 bV = *(const short8*)&vcur[(unsigned)(nb * 32 + l31) * 64 +
                                                  ((kc * 2 + half) ^ xsw) * 8];
          o[nb] = __builtin_amdgcn_mfma_f32_32x32x16_bf16(cv.s8, bV, o[nb], 0, 0, 0);
        }
        o_l = __builtin_amdgcn_mfma_f32_32x32x16_bf16(cv.s8, ones, o_l, 0, 0, 0);
        __builtin_amdgcn_s_setprio(0);
      }
    }
    __syncthreads();  // staged next tile complete; buffers free for overwrite
  }

  // Epilogue: o_l rows align with o rows (same A-op, same MFMA shape), so
  // normalization is purely lane-local. ctx write coalesced over l31.
  const int b = bh >> 4;
  const int h = bh & 15;
#pragma unroll
  for (int gq = 0; gq < 4; gq++)
#pragma unroll
    for (int j = 0; j < 4; j++) {
      int r = gq * 4 + j;
      int ql = j + gq * 8 + half * 4;  // q within wave (C-layout row)
      float inv = __builtin_amdgcn_rcpf(o_l[r]);
      int token = qt * 128 + wave * 32 + ql;
#pragma unroll
      for (int nb = 0; nb < 2; nb++)
        ctx[((size_t)b * SEQ + token) * DM + h * DH + nb * 32 + l31] =
            f2bf(o[nb][r] * inv);
    }
}

extern "C" void kernel_launch(void* const* d_in, const int* in_sizes, int n_in,
                              void* d_out, int out_size, void* d_ws,
                              size_t ws_size, hipStream_t stream) {
  const float* x = (const float*)d_in[0];     // [8192,1024] fp32
  const float* Wqkv = (const float*)d_in[1];  // [1024,3072] fp32
  const float* Wo = (const float*)d_in[2];    // [1024,1024] fp32
  float* out = (float*)d_out;                 // [8192,1024] fp32
  unsigned short* ws = (unsigned short*)d_ws;

  unsigned short* Qb = ws;                          // [bh][T][64], pre-scaled
  unsigned short* Kb = ws + SEG;                    // [bh][T][64]
  unsigned short* Vt = ws + 2 * SEG;                // [bh][64][T]
  unsigned short* Ctx = ws + 3 * SEG;               // [8192][1024]
  unsigned short* WqT = Ctx + (size_t)MTOK * DM;    // [3072][1024]
  unsigned short* WoT = WqT + (size_t)3 * DM * DM;  // [1024][1024]
  unsigned short* Xb = WoT + (size_t)DM * DM;       // [8192][1024]
  const size_t need =
      ((size_t)(Xb - ws) + (size_t)MTOK * DM) * sizeof(unsigned short);

  transpose_w<<<dim3(3 * DM / 64, DM / 64), 256, 0, stream>>>(Wqkv, WqT, DM, 3 * DM);
  transpose_w<<<dim3(DM / 64, DM / 64), 256, 0, stream>>>(Wo, WoT, DM, DM);

  if (ws_size >= need) {
    xcast<<<(MTOK * DM) / (256 * 8), 256, 0, stream>>>(x, Xb);
    gemm_kernel<2><<<dim3(3 * DM / 128, MTOK / 128), 256, 0, stream>>>(
        (const void*)Xb, WqT, Qb, Kb, Vt, nullptr, MTOK, 3 * DM, DM);
  } else {
    gemm_kernel<0><<<dim3(3 * DM / 128, MTOK / 128), 256, 0, stream>>>(
        (const void*)x, WqT, Qb, Kb, Vt, nullptr, MTOK, 3 * DM, DM);
  }
  attn_kernel<<<dim3(SEQ / 128 * NBATCH * NH), 256, 0, stream>>>(Qb, Kb, Vt, Ctx);
  gemm_kernel<1><<<dim3(DM / 128, MTOK / 128), 256, 0, stream>>>(
      (const void*)Ctx, WoT, nullptr, nullptr, nullptr, out, MTOK, DM, DM);
}